// Round 14
// baseline (273.448 us; speedup 1.0000x reference)
//
#include <hip/hip_runtime.h>
#include <math.h>

#define NN    8192
#define NODES 16384
#define KK    40
#define CAP   256

// Round 14: identical arithmetic family (absmax 0.04296875, r10-r13). knn:
// drop binv LDS entirely — pass B recomputes keys (L2-resident s4), merging
// the candidate exact-key path. LDS 21.5KB -> ~5.5KB -> 8 blocks/CU (100%).

__device__ __forceinline__ float r14_elu(float x){ return x > 0.f ? x : expm1f(x); }

// family-A d2 key expression — verbatim from r10..r13 (contract ON)
__device__ __forceinline__ unsigned r14_key(float4 si, float4 sj){
  float dot = si.x*sj.x + si.y*sj.y + si.z*sj.z;
  float d2 = si.w + sj.w - 2.0f*dot;
  d2 = fmaxf(d2, 0.0f);
  return __float_as_uint(d2);
}

// ---------------- K1: pre-MLP + fused BN1 partials — UNCHANGED from r13
__global__ __launch_bounds__(256) void r14_pre(const float* __restrict__ x,
    const float* __restrict__ W1, const float* __restrict__ b1,
    const float* __restrict__ W2, const float* __restrict__ b2,
    float* __restrict__ xpre, float* __restrict__ part1)
{
  __shared__ float sW1[9*32], sb1[32], sW2[32*32], sb2[32];
  __shared__ float wls[4][32], wls2[4][32];
  int t = threadIdx.x;
  for (int i = t; i < 9*32;  i += 256) sW1[i] = W1[i];
  for (int i = t; i < 32*32; i += 256) sW2[i] = W2[i];
  if (t < 32) { sb1[t] = b1[t]; sb2[t] = b2[t]; }
  __syncthreads();
  int node = blockIdx.x*256 + t;
  float xv[9], a1[32], a2[32];
  #pragma unroll
  for (int i=0;i<9;i++) xv[i] = x[node*9+i];
  #pragma unroll
  for (int o=0;o<32;o++){
    float a = sb1[o];
    #pragma unroll
    for (int i=0;i<9;i++) a += xv[i]*sW1[i*32+o];
    a1[o] = r14_elu(a);
  }
  #pragma unroll
  for (int o=0;o<32;o++){
    float a = sb2[o];
    #pragma unroll
    for (int i=0;i<32;i++) a += a1[i]*sW2[i*32+o];
    a2[o] = r14_elu(a);
    xpre[(size_t)node*32+o] = a2[o];
  }
  int lane = t & 63, w = t >> 6;
  #pragma unroll
  for (int c=0;c<32;c++){
    float v = a2[c], v2 = a2[c]*a2[c];
    #pragma unroll
    for (int off=32; off; off>>=1){ v += __shfl_down(v,(unsigned)off,64); v2 += __shfl_down(v2,(unsigned)off,64); }
    if (lane==0){ wls[w][c]=v; wls2[w][c]=v2; }
  }
  __syncthreads();
  if (t < 32){
    part1[blockIdx.x*64 + t]      = wls[0][t]+wls[1][t]+wls[2][t]+wls[3][t];
    part1[blockIdx.x*64 + 32 + t] = wls2[0][t]+wls2[1][t]+wls2[2][t]+wls2[3][t];
  }
}

// ---------------- K2: fused sred + BN1 apply + projections — UNCHANGED
__global__ __launch_bounds__(256) void r14_bnproj(const float* __restrict__ part1,
    const float* __restrict__ xpre,
    const float* __restrict__ bng, const float* __restrict__ bnb,
    const float* __restrict__ hW, const float* __restrict__ hb, const float* __restrict__ sW,
    float* __restrict__ x1, float* __restrict__ h, float4* __restrict__ s4)
{
  __shared__ float sHW[32*32], sHB[32], sSW[32*3];
  __shared__ float sstat[64];
  __shared__ float smu[32], sdev[32], sg[32], sbt[32];
  int t = threadIdx.x;
  for (int i=t;i<1024;i+=256) sHW[i]=hW[i];
  if (t < 96) sSW[t]=sW[t];
  if (t < 64){
    float s = 0.f;
    for (int b2=0;b2<64;b2++) s += part1[b2*64+t];
    sstat[t] = s;
  }
  __syncthreads();
  if (t < 32){
    sHB[t]=hb[t];
    float s = sstat[t], sq = sstat[32+t];
    float mu = s * (1.f/NODES);
    float var = sq * (1.f/NODES) - mu*mu;
    smu[t]=mu; sdev[t]=sqrtf(var+1e-5f);
    sg[t]=bng[t]; sbt[t]=bnb[t];
  }
  __syncthreads();
  int node = blockIdx.x*256+t;
  float v[32];
  #pragma unroll
  for (int c=0;c<32;c++){
    float a = xpre[(size_t)node*32+c];
    v[c] = sg[c]*(a - smu[c])/sdev[c] + sbt[c];
    x1[(size_t)node*32+c] = v[c];
  }
  #pragma unroll
  for (int o=0;o<32;o++){
    float a = sHB[o];
    #pragma unroll
    for (int i=0;i<32;i++) a += v[i]*sHW[i*32+o];
    h[(size_t)node*32+o] = a;
  }
  float s0=0.f,s1=0.f,s2=0.f;
  #pragma unroll
  for (int i=0;i<32;i++){
    s0 += v[i]*sSW[i*3+0];
    s1 += v[i]*sSW[i*3+1];
    s2 += v[i]*sSW[i*3+2];
  }
  float n2 = s0*s0 + s1*s1 + s2*s2;
  s4[node] = make_float4(s0,s1,s2,n2);
}

// ---------------- K3: kNN — hist-only pass A, recompute pass B, tiny LDS
__global__ __launch_bounds__(256) void r14_knn(const float4* __restrict__ s4,
    const float* __restrict__ h, float* __restrict__ agg)
{
  __shared__ unsigned hist[1024];        // 4 KB; overlaid later by cand/psum/pmax
  __shared__ int      sel[KK];
  __shared__ unsigned selk[KK];
  __shared__ float    pots[KK];
  __shared__ unsigned wsum[4], wtot[4];
  __shared__ unsigned sB1, sL1, candCount;

  int t = threadIdx.x;
  int lane = t & 63, w = t >> 6;
  int b = blockIdx.x >> 13;
  int i = blockIdx.x & (NN-1);
  const float4* sb = s4 + (size_t)b*NN;
  float4 si = sb[i];

  #pragma unroll
  for (int z=0; z<4; ++z) hist[z*256 + t] = 0u;
  if (t == 0) candCount = 0u;
  __syncthreads();

  // pass A: keys -> histogram only (no LDS key storage)
  #pragma unroll 4
  for (int c=0;c<32;c++){
    int j = c*256 + t;
    unsigned k = r14_key(si, sb[j]);
    if (j == i) k = 0x7F800000u;
    atomicAdd(&hist[k>>21], 1u);
  }
  __syncthreads();

  // scan 1024 bins (4/thread), locate rank-40 bucket (identical to r12/r13)
  unsigned c0 = hist[4*t+0], c1 = hist[4*t+1], c2 = hist[4*t+2], c3 = hist[4*t+3];
  unsigned chunk = c0+c1+c2+c3;
  unsigned sc = chunk;
  #pragma unroll
  for (int off=1; off<64; off<<=1){
    unsigned o = __shfl_up(sc, (unsigned)off, 64);
    if (lane >= off) sc += o;
  }
  if (lane == 63) wsum[w] = sc;
  __syncthreads();
  unsigned base = 0;
  for (int w2=0; w2<w; ++w2) base += wsum[w2];
  unsigned excl = base + sc - chunk;
  if (excl < KK && KK <= excl + chunk){
    unsigned acc = excl; int bb = 4*t;
    if (acc + c0 >= KK){ sB1 = (unsigned)bb;   sL1 = acc; }
    else { acc += c0;
      if (acc + c1 >= KK){ sB1 = (unsigned)(bb+1); sL1 = acc; }
      else { acc += c1;
        if (acc + c2 >= KK){ sB1 = (unsigned)(bb+2); sL1 = acc; }
        else { acc += c2;    sB1 = (unsigned)(bb+3); sL1 = acc; } } }
  }
  __syncthreads();
  unsigned B1 = sB1, L1 = sL1;
  unsigned* candk = &hist[0];      // hist dead after scan
  unsigned* candj = &hist[CAP];

  // pass B: recompute keys; masks + candidate append (exact key in hand)
  unsigned lessmask = 0; unsigned cnt = 0;
  unsigned mykey[32];
  #pragma unroll 4
  for (int c=0;c<32;c++){
    int j = c*256 + t;
    unsigned k = r14_key(si, sb[j]);
    if (j == i) k = 0x7F800000u;
    mykey[c] = k;
    unsigned bin = k >> 21;
    if (bin < B1){ lessmask |= 1u<<c; cnt++; }
  }
  unsigned v = cnt;
  #pragma unroll
  for (int off=1; off<64; off<<=1){
    unsigned o = __shfl_up(v, (unsigned)off, 64);
    if (lane >= off) v += o;
  }
  if (lane == 63) wtot[w] = v;
  __syncthreads();
  unsigned gbase = 0;
  for (int w2=0; w2<w; ++w2) gbase += wtot[w2];
  unsigned offs = gbase + v - cnt;
  #pragma unroll 4
  for (int c=0;c<32;c++){
    int j = c*256+t;
    unsigned k = mykey[c];
    unsigned bin = k >> 21;
    if ((lessmask>>c)&1u){ sel[offs] = j; offs++; }
    else if (bin == B1){
      unsigned slot = atomicAdd(&candCount, 1u);
      if (slot < CAP){ candk[slot] = k; candj[slot] = (unsigned)j; }
    }
  }
  __syncthreads();

  // exact lex rank (key, j) among candidates; ranks L1..39 fill sel/selk
  unsigned C1 = candCount; if (C1 > CAP) C1 = CAP;
  for (unsigned idx = (unsigned)t; idx < C1; idx += 256){
    unsigned k = candk[idx], j = candj[idx];
    unsigned rank = L1;
    for (unsigned u=0; u<C1; ++u){
      unsigned ku = candk[u], ju = candj[u];
      rank += (ku < k || (ku == k && ju < j)) ? 1u : 0u;
    }
    if (rank < KK){ sel[rank] = (int)j; selk[rank] = k; }
  }
  __syncthreads();
  if (t < (int)L1) selk[t] = r14_key(si, sb[sel[t]]);  // exact keys for pots
  __syncthreads();

  // potentials + aggregation (identical structure to r11..r13)
  if (t < KK) pots[t] = expf(-__uint_as_float(selk[t]));
  __syncthreads();
  float (*psum)[32] = (float(*)[32])&hist[512];
  float (*pmax)[32] = (float(*)[32])&hist[768];
  int ch = t & 31, g = t >> 5;
  const float* hb2 = h + (size_t)b*NN*32;
  float sum = 0.f, mx = -INFINITY;
  #pragma unroll
  for (int q=0;q<5;q++){
    int k2 = g*5 + q;
    float m = pots[k2] * hb2[(size_t)sel[k2]*32 + ch];
    sum += m; mx = fmaxf(mx, m);
  }
  psum[g][ch] = sum; pmax[g][ch] = mx;
  __syncthreads();
  if (t < 32){
    float s = 0.f, m2 = -INFINITY;
    #pragma unroll
    for (int g2=0;g2<8;g2++){ s += psum[g2][t]; m2 = fmaxf(m2, pmax[g2][t]); }
    float* ab = agg + (size_t)blockIdx.x*64;
    ab[t]    = s / 40.0f;
    ab[32+t] = m2;
  }
}

// ---------------- K4: lin + post-MLP + fused BN2 partials — UNCHANGED
__global__ __launch_bounds__(256) void r14_post(const float* __restrict__ agg,
    const float* __restrict__ x1, const float4* __restrict__ s4,
    const float* __restrict__ linW, const float* __restrict__ linb,
    const float* __restrict__ pW1, const float* __restrict__ pb1,
    const float* __restrict__ pW2, const float* __restrict__ pb2,
    float* __restrict__ outpre, float* __restrict__ part2)
{
  __shared__ float sLW[96*32], sPW1[67*32], sPW2[32*32];
  __shared__ float sLB[32], sPB1[32], sPB2[32];
  __shared__ float wls[4][32], wls2[4][32];
  int t = threadIdx.x;
  for (int i=t;i<96*32;i+=256) sLW[i]=linW[i];
  for (int i=t;i<67*32;i+=256) sPW1[i]=pW1[i];
  for (int i=t;i<32*32;i+=256) sPW2[i]=pW2[i];
  if (t<32){ sLB[t]=linb[t]; sPB1[t]=pb1[t]; sPB2[t]=pb2[t]; }
  __syncthreads();
  int node = blockIdx.x*256+t;
  float av[64], xv[32];
  #pragma unroll
  for (int i=0;i<64;i++) av[i]=agg[(size_t)node*64+i];
  #pragma unroll
  for (int i=0;i<32;i++) xv[i]=x1[(size_t)node*32+i];
  float4 sv = s4[node];
  float xgn[32];
  #pragma unroll
  for (int o=0;o<32;o++){
    float a = sLB[o];
    #pragma unroll
    for (int i=0;i<64;i++) a += av[i]*sLW[i*32+o];
    #pragma unroll
    for (int i=0;i<32;i++) a += xv[i]*sLW[(64+i)*32+o];
    xgn[o]=a;
  }
  float p1[32];
  #pragma unroll
  for (int o=0;o<32;o++){
    float a = sPB1[o];
    #pragma unroll
    for (int i=0;i<32;i++) a += xgn[i]*sPW1[i*32+o];
    a += sv.x*sPW1[32*32+o] + sv.y*sPW1[33*32+o] + sv.z*sPW1[34*32+o];
    #pragma unroll
    for (int i=0;i<32;i++) a += xv[i]*sPW1[(35+i)*32+o];
    p1[o]=r14_elu(a);
  }
  float p2[32];
  #pragma unroll
  for (int o=0;o<32;o++){
    float a = sPB2[o];
    #pragma unroll
    for (int i=0;i<32;i++) a += p1[i]*sPW2[i*32+o];
    p2[o] = r14_elu(a);
    outpre[(size_t)node*32+o] = p2[o];
  }
  int lane = t & 63, w = t >> 6;
  #pragma unroll
  for (int c=0;c<32;c++){
    float v = p2[c], v2 = p2[c]*p2[c];
    #pragma unroll
    for (int off=32; off; off>>=1){ v += __shfl_down(v,(unsigned)off,64); v2 += __shfl_down(v2,(unsigned)off,64); }
    if (lane==0){ wls[w][c]=v; wls2[w][c]=v2; }
  }
  __syncthreads();
  if (t < 32){
    part2[blockIdx.x*64 + t]      = wls[0][t]+wls[1][t]+wls[2][t]+wls[3][t];
    part2[blockIdx.x*64 + 32 + t] = wls2[0][t]+wls2[1][t]+wls2[2][t]+wls2[3][t];
  }
}

// ---------------- K5: fused sred2 + BN2 apply -> d_out — UNCHANGED
__global__ __launch_bounds__(256) void r14_bnout(const float* __restrict__ part2,
    const float* __restrict__ outpre,
    const float* __restrict__ g, const float* __restrict__ b,
    float* __restrict__ out)
{
  __shared__ float sstat[64];
  __shared__ float smu[32], sdev2[32], sg2[32], sb2[32];
  int t = threadIdx.x;
  if (t < 64){
    float s = 0.f;
    for (int b2=0;b2<64;b2++) s += part2[b2*64+t];
    sstat[t] = s;
  }
  __syncthreads();
  if (t < 32){
    float s = sstat[t], sq = sstat[32+t];
    float mu = s * (1.f/NODES);
    float var = sq*(1.f/NODES) - mu*mu;
    smu[t] = mu; sdev2[t] = sqrtf(var+1e-5f);
    sg2[t] = g[t]; sb2[t] = b[t];
  }
  __syncthreads();
  int idx = blockIdx.x*256 + t;
  int c = idx & 31;
  out[idx] = sg2[c]*(outpre[idx]-smu[c])/sdev2[c] + sb2[c];
}

extern "C" void kernel_launch(void* const* d_in, const int* in_sizes, int n_in,
                              void* d_out, int out_size, void* d_ws, size_t ws_size,
                              hipStream_t stream)
{
  (void)in_sizes; (void)n_in; (void)out_size; (void)ws_size;
  const float* x      = (const float*)d_in[0];
  const float* preW1  = (const float*)d_in[1];
  const float* preb1  = (const float*)d_in[2];
  const float* preW2  = (const float*)d_in[3];
  const float* preb2  = (const float*)d_in[4];
  const float* bn1g   = (const float*)d_in[5];
  const float* bn1b   = (const float*)d_in[6];
  const float* linsW  = (const float*)d_in[7];
  const float* linhW  = (const float*)d_in[8];
  const float* linhb  = (const float*)d_in[9];
  const float* linW   = (const float*)d_in[10];
  const float* linb   = (const float*)d_in[11];
  const float* postW1 = (const float*)d_in[12];
  const float* postb1 = (const float*)d_in[13];
  const float* postW2 = (const float*)d_in[14];
  const float* postb2 = (const float*)d_in[15];
  const float* bn2g   = (const float*)d_in[16];
  const float* bn2b   = (const float*)d_in[17];

  float* ws = (float*)d_ws;
  float* xpre   = ws;                          // NODES*32
  float* x1     = xpre   + (size_t)NODES*32;
  float* h      = x1     + (size_t)NODES*32;
  float* s4     = h      + (size_t)NODES*32;   // NODES*4 (16B-aligned offset)
  float* agg    = s4     + (size_t)NODES*4;    // NODES*64
  float* outpre = agg    + (size_t)NODES*64;   // NODES*32
  float* part1  = outpre + (size_t)NODES*32;   // 64*64
  float* part2  = part1  + 64*64;              // 64*64

  hipLaunchKernelGGL(r14_pre,    dim3(64),    dim3(256), 0, stream, x, preW1, preb1, preW2, preb2, xpre, part1);
  hipLaunchKernelGGL(r14_bnproj, dim3(64),    dim3(256), 0, stream, part1, xpre, bn1g, bn1b, linhW, linhb, linsW, x1, h, (float4*)s4);
  hipLaunchKernelGGL(r14_knn,    dim3(16384), dim3(256), 0, stream, (const float4*)s4, h, agg);
  hipLaunchKernelGGL(r14_post,   dim3(64),    dim3(256), 0, stream, agg, x1, (const float4*)s4, linW, linb, postW1, postb1, postW2, postb2, outpre, part2);
  hipLaunchKernelGGL(r14_bnout,  dim3(2048),  dim3(256), 0, stream, part2, outpre, bn2g, bn2b, (float*)d_out);
}

// Round 15
// 233.382 us; speedup vs baseline: 1.1717x; 1.1717x over previous
//
#include <hip/hip_runtime.h>
#include <math.h>

#define NN    8192
#define NODES 16384
#define KK    40
#define CAP   256

// Round 15: identical arithmetic family (absmax 0.04296875, r10-r14). knn:
// Q=4 queries per block — sb[j] load + addressing amortized over 4 keys.
// Selection logic verbatim per query -> identical selected sets.

__device__ __forceinline__ float r15_elu(float x){ return x > 0.f ? x : expm1f(x); }

// family-A d2 key expression — verbatim from r10..r14 (contract ON)
__device__ __forceinline__ unsigned r15_key(float4 si, float4 sj){
  float dot = si.x*sj.x + si.y*sj.y + si.z*sj.z;
  float d2 = si.w + sj.w - 2.0f*dot;
  d2 = fmaxf(d2, 0.0f);
  return __float_as_uint(d2);
}

// ---------------- K1: pre-MLP + fused BN1 partials — UNCHANGED
__global__ __launch_bounds__(256) void r15_pre(const float* __restrict__ x,
    const float* __restrict__ W1, const float* __restrict__ b1,
    const float* __restrict__ W2, const float* __restrict__ b2,
    float* __restrict__ xpre, float* __restrict__ part1)
{
  __shared__ float sW1[9*32], sb1[32], sW2[32*32], sb2[32];
  __shared__ float wls[4][32], wls2[4][32];
  int t = threadIdx.x;
  for (int i = t; i < 9*32;  i += 256) sW1[i] = W1[i];
  for (int i = t; i < 32*32; i += 256) sW2[i] = W2[i];
  if (t < 32) { sb1[t] = b1[t]; sb2[t] = b2[t]; }
  __syncthreads();
  int node = blockIdx.x*256 + t;
  float xv[9], a1[32], a2[32];
  #pragma unroll
  for (int i=0;i<9;i++) xv[i] = x[node*9+i];
  #pragma unroll
  for (int o=0;o<32;o++){
    float a = sb1[o];
    #pragma unroll
    for (int i=0;i<9;i++) a += xv[i]*sW1[i*32+o];
    a1[o] = r15_elu(a);
  }
  #pragma unroll
  for (int o=0;o<32;o++){
    float a = sb2[o];
    #pragma unroll
    for (int i=0;i<32;i++) a += a1[i]*sW2[i*32+o];
    a2[o] = r15_elu(a);
    xpre[(size_t)node*32+o] = a2[o];
  }
  int lane = t & 63, w = t >> 6;
  #pragma unroll
  for (int c=0;c<32;c++){
    float v = a2[c], v2 = a2[c]*a2[c];
    #pragma unroll
    for (int off=32; off; off>>=1){ v += __shfl_down(v,(unsigned)off,64); v2 += __shfl_down(v2,(unsigned)off,64); }
    if (lane==0){ wls[w][c]=v; wls2[w][c]=v2; }
  }
  __syncthreads();
  if (t < 32){
    part1[blockIdx.x*64 + t]      = wls[0][t]+wls[1][t]+wls[2][t]+wls[3][t];
    part1[blockIdx.x*64 + 32 + t] = wls2[0][t]+wls2[1][t]+wls2[2][t]+wls2[3][t];
  }
}

// ---------------- K2: fused sred + BN1 apply + projections — UNCHANGED
__global__ __launch_bounds__(256) void r15_bnproj(const float* __restrict__ part1,
    const float* __restrict__ xpre,
    const float* __restrict__ bng, const float* __restrict__ bnb,
    const float* __restrict__ hW, const float* __restrict__ hb, const float* __restrict__ sW,
    float* __restrict__ x1, float* __restrict__ h, float4* __restrict__ s4)
{
  __shared__ float sHW[32*32], sHB[32], sSW[32*3];
  __shared__ float sstat[64];
  __shared__ float smu[32], sdev[32], sg[32], sbt[32];
  int t = threadIdx.x;
  for (int i=t;i<1024;i+=256) sHW[i]=hW[i];
  if (t < 96) sSW[t]=sW[t];
  if (t < 64){
    float s = 0.f;
    for (int b2=0;b2<64;b2++) s += part1[b2*64+t];
    sstat[t] = s;
  }
  __syncthreads();
  if (t < 32){
    sHB[t]=hb[t];
    float s = sstat[t], sq = sstat[32+t];
    float mu = s * (1.f/NODES);
    float var = sq * (1.f/NODES) - mu*mu;
    smu[t]=mu; sdev[t]=sqrtf(var+1e-5f);
    sg[t]=bng[t]; sbt[t]=bnb[t];
  }
  __syncthreads();
  int node = blockIdx.x*256+t;
  float v[32];
  #pragma unroll
  for (int c=0;c<32;c++){
    float a = xpre[(size_t)node*32+c];
    v[c] = sg[c]*(a - smu[c])/sdev[c] + sbt[c];
    x1[(size_t)node*32+c] = v[c];
  }
  #pragma unroll
  for (int o=0;o<32;o++){
    float a = sHB[o];
    #pragma unroll
    for (int i=0;i<32;i++) a += v[i]*sHW[i*32+o];
    h[(size_t)node*32+o] = a;
  }
  float s0=0.f,s1=0.f,s2=0.f;
  #pragma unroll
  for (int i=0;i<32;i++){
    s0 += v[i]*sSW[i*3+0];
    s1 += v[i]*sSW[i*3+1];
    s2 += v[i]*sSW[i*3+2];
  }
  float n2 = s0*s0 + s1*s1 + s2*s2;
  s4[node] = make_float4(s0,s1,s2,n2);
}

// ---------------- K3: kNN — Q=4 queries per block
__global__ __launch_bounds__(256) void r15_knn(const float4* __restrict__ s4,
    const float* __restrict__ h, float* __restrict__ agg)
{
  __shared__ unsigned hist[4][1024];   // 16 KB; overlaid after scan
  __shared__ int      sel[4][KK];
  __shared__ unsigned selk[4][KK];
  __shared__ float    pots[4][KK];
  __shared__ unsigned wsum[4];
  __shared__ unsigned wtot[4][4];      // [q][wave]
  __shared__ unsigned sB1[4], sL1[4], candCount[4];

  int t = threadIdx.x;
  int lane = t & 63, w = t >> 6;
  int b  = blockIdx.x >> 11;           // 4096 blocks: 2048 per graph
  int i0 = (blockIdx.x & 2047) * 4;
  const float4* sb = s4 + (size_t)b*NN;
  float4 si[4]; int iq[4];
  #pragma unroll
  for (int q=0;q<4;q++){ iq[q] = i0+q; si[q] = sb[i0+q]; }

  unsigned* histf = (unsigned*)hist;
  #pragma unroll
  for (int z=0; z<16; ++z) histf[z*256 + t] = 0u;
  if (t < 4) candCount[t] = 0u;
  __syncthreads();

  // pass A: keys -> per-query histograms
  #pragma unroll 2
  for (int c=0;c<32;c++){
    int j = c*256 + t;
    float4 sj = sb[j];
    #pragma unroll
    for (int q=0;q<4;q++){
      unsigned k = r15_key(si[q], sj);
      if (j == iq[q]) k = 0x7F800000u;
      atomicAdd(&hist[q][k>>21], 1u);
    }
  }
  __syncthreads();

  // per-query scan over 1024 bins (4/thread), locate rank-40 bucket
  for (int q=0;q<4;q++){
    unsigned c0 = hist[q][4*t+0], c1 = hist[q][4*t+1], c2 = hist[q][4*t+2], c3 = hist[q][4*t+3];
    unsigned chunk = c0+c1+c2+c3;
    unsigned sc = chunk;
    #pragma unroll
    for (int off=1; off<64; off<<=1){
      unsigned o = __shfl_up(sc, (unsigned)off, 64);
      if (lane >= off) sc += o;
    }
    if (lane == 63) wsum[w] = sc;
    __syncthreads();
    unsigned base = 0;
    for (int w2=0; w2<w; ++w2) base += wsum[w2];
    unsigned excl = base + sc - chunk;
    if (excl < KK && KK <= excl + chunk){
      unsigned acc = excl; int bb = 4*t;
      if (acc + c0 >= KK){ sB1[q] = (unsigned)bb;   sL1[q] = acc; }
      else { acc += c0;
        if (acc + c1 >= KK){ sB1[q] = (unsigned)(bb+1); sL1[q] = acc; }
        else { acc += c1;
          if (acc + c2 >= KK){ sB1[q] = (unsigned)(bb+2); sL1[q] = acc; }
          else { acc += c2;    sB1[q] = (unsigned)(bb+3); sL1[q] = acc; } } }
    }
    __syncthreads();                      // also protects wsum reuse
  }
  unsigned B1r[4];
  #pragma unroll
  for (int q=0;q<4;q++) B1r[q] = sB1[q];
  unsigned* candk = &histf[0];            // [q*CAP + slot], hist dead
  unsigned* candj = &histf[1024];

  // pass B: recompute keys once; masks + candidate append (exact key in hand)
  unsigned lessm[4] = {0,0,0,0};
  unsigned cnt[4]   = {0,0,0,0};
  #pragma unroll 2
  for (int c=0;c<32;c++){
    int j = c*256 + t;
    float4 sj = sb[j];
    #pragma unroll
    for (int q=0;q<4;q++){
      unsigned k = r15_key(si[q], sj);
      if (j == iq[q]) k = 0x7F800000u;
      unsigned bin = k >> 21;
      if (bin < B1r[q]){ lessm[q] |= 1u<<c; cnt[q]++; }
      else if (bin == B1r[q]){
        unsigned slot = atomicAdd(&candCount[q], 1u);
        if (slot < CAP){ candk[q*CAP+slot] = k; candj[q*CAP+slot] = (unsigned)j; }
      }
    }
  }
  // per-query wave-scan compaction of strict-less
  unsigned vq[4];
  #pragma unroll
  for (int q=0;q<4;q++){
    unsigned v = cnt[q];
    #pragma unroll
    for (int off=1; off<64; off<<=1){
      unsigned o = __shfl_up(v, (unsigned)off, 64);
      if (lane >= off) v += o;
    }
    if (lane == 63) wtot[q][w] = v;
    vq[q] = v;
  }
  __syncthreads();
  #pragma unroll
  for (int q=0;q<4;q++){
    unsigned gbase = 0;
    for (int w2=0; w2<w; ++w2) gbase += wtot[q][w2];
    unsigned offs = gbase + vq[q] - cnt[q];
    unsigned m = lessm[q];
    while (m){
      int c = __builtin_ctz(m); m &= m-1u;
      sel[q][offs++] = c*256 + t;
    }
  }
  __syncthreads();

  // exact lex rank (key, j) among candidates; ranks L1..39 fill sel/selk
  for (int q=0;q<4;q++){
    unsigned C1 = candCount[q]; if (C1 > CAP) C1 = CAP;
    unsigned L1 = sL1[q];
    for (unsigned idx = (unsigned)t; idx < C1; idx += 256){
      unsigned k = candk[q*CAP+idx], j = candj[q*CAP+idx];
      unsigned rank = L1;
      for (unsigned u=0; u<C1; ++u){
        unsigned ku = candk[q*CAP+u], ju = candj[q*CAP+u];
        rank += (ku < k || (ku == k && ju < j)) ? 1u : 0u;
      }
      if (rank < KK){ sel[q][rank] = (int)j; selk[q][rank] = k; }
    }
  }
  __syncthreads();
  #pragma unroll
  for (int q=0;q<4;q++){
    if (t < (int)sL1[q]) selk[q][t] = r15_key(si[q], sb[sel[q][t]]);
  }
  __syncthreads();
  if (t < KK){
    #pragma unroll
    for (int q=0;q<4;q++) pots[q][t] = expf(-__uint_as_float(selk[q][t]));
  }
  __syncthreads();

  // aggregation per query (identical structure to r11..r14)
  float (*psum)[32] = (float(*)[32])&histf[2048];
  float (*pmax)[32] = (float(*)[32])&histf[2304];
  int ch = t & 31, g = t >> 5;
  const float* hb2 = h + (size_t)b*NN*32;
  for (int q=0;q<4;q++){
    float sum = 0.f, mx = -INFINITY;
    #pragma unroll
    for (int p=0;p<5;p++){
      int k2 = g*5 + p;
      float m = pots[q][k2] * hb2[(size_t)sel[q][k2]*32 + ch];
      sum += m; mx = fmaxf(mx, m);
    }
    psum[g][ch] = sum; pmax[g][ch] = mx;
    __syncthreads();
    if (t < 32){
      float s = 0.f, m2 = -INFINITY;
      #pragma unroll
      for (int g2=0;g2<8;g2++){ s += psum[g2][t]; m2 = fmaxf(m2, pmax[g2][t]); }
      float* ab = agg + (size_t)(b*NN + i0 + q)*64;
      ab[t]    = s / 40.0f;
      ab[32+t] = m2;
    }
    __syncthreads();
  }
}

// ---------------- K4: lin + post-MLP + fused BN2 partials — UNCHANGED
__global__ __launch_bounds__(256) void r15_post(const float* __restrict__ agg,
    const float* __restrict__ x1, const float4* __restrict__ s4,
    const float* __restrict__ linW, const float* __restrict__ linb,
    const float* __restrict__ pW1, const float* __restrict__ pb1,
    const float* __restrict__ pW2, const float* __restrict__ pb2,
    float* __restrict__ outpre, float* __restrict__ part2)
{
  __shared__ float sLW[96*32], sPW1[67*32], sPW2[32*32];
  __shared__ float sLB[32], sPB1[32], sPB2[32];
  __shared__ float wls[4][32], wls2[4][32];
  int t = threadIdx.x;
  for (int i=t;i<96*32;i+=256) sLW[i]=linW[i];
  for (int i=t;i<67*32;i+=256) sPW1[i]=pW1[i];
  for (int i=t;i<32*32;i+=256) sPW2[i]=pW2[i];
  if (t<32){ sLB[t]=linb[t]; sPB1[t]=pb1[t]; sPB2[t]=pb2[t]; }
  __syncthreads();
  int node = blockIdx.x*256+t;
  float av[64], xv[32];
  #pragma unroll
  for (int i=0;i<64;i++) av[i]=agg[(size_t)node*64+i];
  #pragma unroll
  for (int i=0;i<32;i++) xv[i]=x1[(size_t)node*32+i];
  float4 sv = s4[node];
  float xgn[32];
  #pragma unroll
  for (int o=0;o<32;o++){
    float a = sLB[o];
    #pragma unroll
    for (int i=0;i<64;i++) a += av[i]*sLW[i*32+o];
    #pragma unroll
    for (int i=0;i<32;i++) a += xv[i]*sLW[(64+i)*32+o];
    xgn[o]=a;
  }
  float p1[32];
  #pragma unroll
  for (int o=0;o<32;o++){
    float a = sPB1[o];
    #pragma unroll
    for (int i=0;i<32;i++) a += xgn[i]*sPW1[i*32+o];
    a += sv.x*sPW1[32*32+o] + sv.y*sPW1[33*32+o] + sv.z*sPW1[34*32+o];
    #pragma unroll
    for (int i=0;i<32;i++) a += xv[i]*sPW1[(35+i)*32+o];
    p1[o]=r15_elu(a);
  }
  float p2[32];
  #pragma unroll
  for (int o=0;o<32;o++){
    float a = sPB2[o];
    #pragma unroll
    for (int i=0;i<32;i++) a += p1[i]*sPW2[i*32+o];
    p2[o] = r15_elu(a);
    outpre[(size_t)node*32+o] = p2[o];
  }
  int lane = t & 63, w = t >> 6;
  #pragma unroll
  for (int c=0;c<32;c++){
    float v = p2[c], v2 = p2[c]*p2[c];
    #pragma unroll
    for (int off=32; off; off>>=1){ v += __shfl_down(v,(unsigned)off,64); v2 += __shfl_down(v2,(unsigned)off,64); }
    if (lane==0){ wls[w][c]=v; wls2[w][c]=v2; }
  }
  __syncthreads();
  if (t < 32){
    part2[blockIdx.x*64 + t]      = wls[0][t]+wls[1][t]+wls[2][t]+wls[3][t];
    part2[blockIdx.x*64 + 32 + t] = wls2[0][t]+wls2[1][t]+wls2[2][t]+wls2[3][t];
  }
}

// ---------------- K5: fused sred2 + BN2 apply -> d_out — UNCHANGED
__global__ __launch_bounds__(256) void r15_bnout(const float* __restrict__ part2,
    const float* __restrict__ outpre,
    const float* __restrict__ g, const float* __restrict__ b,
    float* __restrict__ out)
{
  __shared__ float sstat[64];
  __shared__ float smu[32], sdev2[32], sg2[32], sb2[32];
  int t = threadIdx.x;
  if (t < 64){
    float s = 0.f;
    for (int b2=0;b2<64;b2++) s += part2[b2*64+t];
    sstat[t] = s;
  }
  __syncthreads();
  if (t < 32){
    float s = sstat[t], sq = sstat[32+t];
    float mu = s * (1.f/NODES);
    float var = sq*(1.f/NODES) - mu*mu;
    smu[t] = mu; sdev2[t] = sqrtf(var+1e-5f);
    sg2[t] = g[t]; sb2[t] = b[t];
  }
  __syncthreads();
  int idx = blockIdx.x*256 + t;
  int c = idx & 31;
  out[idx] = sg2[c]*(outpre[idx]-smu[c])/sdev2[c] + sb2[c];
}

extern "C" void kernel_launch(void* const* d_in, const int* in_sizes, int n_in,
                              void* d_out, int out_size, void* d_ws, size_t ws_size,
                              hipStream_t stream)
{
  (void)in_sizes; (void)n_in; (void)out_size; (void)ws_size;
  const float* x      = (const float*)d_in[0];
  const float* preW1  = (const float*)d_in[1];
  const float* preb1  = (const float*)d_in[2];
  const float* preW2  = (const float*)d_in[3];
  const float* preb2  = (const float*)d_in[4];
  const float* bn1g   = (const float*)d_in[5];
  const float* bn1b   = (const float*)d_in[6];
  const float* linsW  = (const float*)d_in[7];
  const float* linhW  = (const float*)d_in[8];
  const float* linhb  = (const float*)d_in[9];
  const float* linW   = (const float*)d_in[10];
  const float* linb   = (const float*)d_in[11];
  const float* postW1 = (const float*)d_in[12];
  const float* postb1 = (const float*)d_in[13];
  const float* postW2 = (const float*)d_in[14];
  const float* postb2 = (const float*)d_in[15];
  const float* bn2g   = (const float*)d_in[16];
  const float* bn2b   = (const float*)d_in[17];

  float* ws = (float*)d_ws;
  float* xpre   = ws;                          // NODES*32
  float* x1     = xpre   + (size_t)NODES*32;
  float* h      = x1     + (size_t)NODES*32;
  float* s4     = h      + (size_t)NODES*32;   // NODES*4 (16B-aligned offset)
  float* agg    = s4     + (size_t)NODES*4;    // NODES*64
  float* outpre = agg    + (size_t)NODES*64;   // NODES*32
  float* part1  = outpre + (size_t)NODES*32;   // 64*64
  float* part2  = part1  + 64*64;              // 64*64

  hipLaunchKernelGGL(r15_pre,    dim3(64),    dim3(256), 0, stream, x, preW1, preb1, preW2, preb2, xpre, part1);
  hipLaunchKernelGGL(r15_bnproj, dim3(64),    dim3(256), 0, stream, part1, xpre, bn1g, bn1b, linhW, linhb, linsW, x1, h, (float4*)s4);
  hipLaunchKernelGGL(r15_knn,    dim3(4096),  dim3(256), 0, stream, (const float4*)s4, h, agg);
  hipLaunchKernelGGL(r15_post,   dim3(64),    dim3(256), 0, stream, agg, x1, (const float4*)s4, linW, linb, postW1, postb1, postW2, postb2, outpre, part2);
  hipLaunchKernelGGL(r15_bnout,  dim3(2048),  dim3(256), 0, stream, part2, outpre, bn2g, bn2b, (float*)d_out);
}

// Round 16
// 229.084 us; speedup vs baseline: 1.1937x; 1.0188x over previous
//
#include <hip/hip_runtime.h>
#include <math.h>

#define NN    8192
#define NODES 16384
#define KK    40
#define CAP   256

// Round 16: identical arithmetic family (absmax 0.04296875, r10-r15). knn:
// packed u16 dual-query histogram (8KB), per-wave bucket scan, 11KB LDS
// -> 8 blocks/CU (100% occupancy). Selection logic verbatim per query.

__device__ __forceinline__ float r16_elu(float x){ return x > 0.f ? x : expm1f(x); }

// family-A d2 key expression — verbatim from r10..r15 (contract ON)
__device__ __forceinline__ unsigned r16_key(float4 si, float4 sj){
  float dot = si.x*sj.x + si.y*sj.y + si.z*sj.z;
  float d2 = si.w + sj.w - 2.0f*dot;
  d2 = fmaxf(d2, 0.0f);
  return __float_as_uint(d2);
}

// ---------------- K1: pre-MLP + fused BN1 partials — UNCHANGED
__global__ __launch_bounds__(256) void r16_pre(const float* __restrict__ x,
    const float* __restrict__ W1, const float* __restrict__ b1,
    const float* __restrict__ W2, const float* __restrict__ b2,
    float* __restrict__ xpre, float* __restrict__ part1)
{
  __shared__ float sW1[9*32], sb1[32], sW2[32*32], sb2[32];
  __shared__ float wls[4][32], wls2[4][32];
  int t = threadIdx.x;
  for (int i = t; i < 9*32;  i += 256) sW1[i] = W1[i];
  for (int i = t; i < 32*32; i += 256) sW2[i] = W2[i];
  if (t < 32) { sb1[t] = b1[t]; sb2[t] = b2[t]; }
  __syncthreads();
  int node = blockIdx.x*256 + t;
  float xv[9], a1[32], a2[32];
  #pragma unroll
  for (int i=0;i<9;i++) xv[i] = x[node*9+i];
  #pragma unroll
  for (int o=0;o<32;o++){
    float a = sb1[o];
    #pragma unroll
    for (int i=0;i<9;i++) a += xv[i]*sW1[i*32+o];
    a1[o] = r16_elu(a);
  }
  #pragma unroll
  for (int o=0;o<32;o++){
    float a = sb2[o];
    #pragma unroll
    for (int i=0;i<32;i++) a += a1[i]*sW2[i*32+o];
    a2[o] = r16_elu(a);
    xpre[(size_t)node*32+o] = a2[o];
  }
  int lane = t & 63, w = t >> 6;
  #pragma unroll
  for (int c=0;c<32;c++){
    float v = a2[c], v2 = a2[c]*a2[c];
    #pragma unroll
    for (int off=32; off; off>>=1){ v += __shfl_down(v,(unsigned)off,64); v2 += __shfl_down(v2,(unsigned)off,64); }
    if (lane==0){ wls[w][c]=v; wls2[w][c]=v2; }
  }
  __syncthreads();
  if (t < 32){
    part1[blockIdx.x*64 + t]      = wls[0][t]+wls[1][t]+wls[2][t]+wls[3][t];
    part1[blockIdx.x*64 + 32 + t] = wls2[0][t]+wls2[1][t]+wls2[2][t]+wls2[3][t];
  }
}

// ---------------- K2: fused sred + BN1 apply + projections — UNCHANGED
__global__ __launch_bounds__(256) void r16_bnproj(const float* __restrict__ part1,
    const float* __restrict__ xpre,
    const float* __restrict__ bng, const float* __restrict__ bnb,
    const float* __restrict__ hW, const float* __restrict__ hb, const float* __restrict__ sW,
    float* __restrict__ x1, float* __restrict__ h, float4* __restrict__ s4)
{
  __shared__ float sHW[32*32], sHB[32], sSW[32*3];
  __shared__ float sstat[64];
  __shared__ float smu[32], sdev[32], sg[32], sbt[32];
  int t = threadIdx.x;
  for (int i=t;i<1024;i+=256) sHW[i]=hW[i];
  if (t < 96) sSW[t]=sW[t];
  if (t < 64){
    float s = 0.f;
    for (int b2=0;b2<64;b2++) s += part1[b2*64+t];
    sstat[t] = s;
  }
  __syncthreads();
  if (t < 32){
    sHB[t]=hb[t];
    float s = sstat[t], sq = sstat[32+t];
    float mu = s * (1.f/NODES);
    float var = sq * (1.f/NODES) - mu*mu;
    smu[t]=mu; sdev[t]=sqrtf(var+1e-5f);
    sg[t]=bng[t]; sbt[t]=bnb[t];
  }
  __syncthreads();
  int node = blockIdx.x*256+t;
  float v[32];
  #pragma unroll
  for (int c=0;c<32;c++){
    float a = xpre[(size_t)node*32+c];
    v[c] = sg[c]*(a - smu[c])/sdev[c] + sbt[c];
    x1[(size_t)node*32+c] = v[c];
  }
  #pragma unroll
  for (int o=0;o<32;o++){
    float a = sHB[o];
    #pragma unroll
    for (int i=0;i<32;i++) a += v[i]*sHW[i*32+o];
    h[(size_t)node*32+o] = a;
  }
  float s0=0.f,s1=0.f,s2=0.f;
  #pragma unroll
  for (int i=0;i<32;i++){
    s0 += v[i]*sSW[i*3+0];
    s1 += v[i]*sSW[i*3+1];
    s2 += v[i]*sSW[i*3+2];
  }
  float n2 = s0*s0 + s1*s1 + s2*s2;
  s4[node] = make_float4(s0,s1,s2,n2);
}

// ---------------- K3: kNN — Q=4, packed dual-query u16 histogram, 11KB LDS
__global__ __launch_bounds__(256) void r16_knn(const float4* __restrict__ s4,
    const float* __restrict__ h, float* __restrict__ agg)
{
  // word index = q&1, half = q>>1 (low: q0/q1, high: q2/q3)
  __shared__ unsigned hist[2][1024];   // 8 KB; overlaid by cand, then psum/pmax
  __shared__ int      sel[4][KK];
  __shared__ unsigned selk[4][KK];
  __shared__ float    pots[4][KK];
  __shared__ unsigned wtot[4][4];      // [q][wave]
  __shared__ unsigned sB1[4], sL1[4], candCount[4];

  int t = threadIdx.x;
  int lane = t & 63, w = t >> 6;
  int b  = blockIdx.x >> 11;           // 4096 blocks: 2048 per graph
  int i0 = (blockIdx.x & 2047) * 4;
  const float4* sb = s4 + (size_t)b*NN;
  float4 si[4]; int iq[4];
  #pragma unroll
  for (int q=0;q<4;q++){ iq[q] = i0+q; si[q] = sb[i0+q]; }

  unsigned* histf = (unsigned*)hist;
  #pragma unroll
  for (int z=0; z<8; ++z) histf[z*256 + t] = 0u;
  if (t < 4) candCount[t] = 0u;
  __syncthreads();

  // pass A: keys -> packed histograms
  #pragma unroll 2
  for (int c=0;c<32;c++){
    int j = c*256 + t;
    float4 sj = sb[j];
    #pragma unroll
    for (int q=0;q<4;q++){
      unsigned k = r16_key(si[q], sj);
      if (j == iq[q]) k = 0x7F800000u;
      atomicAdd(&hist[q&1][k>>21], (q>>1) ? 0x10000u : 1u);
    }
  }
  __syncthreads();

  // per-wave bucket scan: wave w handles query w (word w&1, half w>>1)
  {
    int q = w;
    unsigned c16[16]; unsigned chunk = 0;
    int base = lane*16;
    #pragma unroll
    for (int jj=0;jj<16;jj++){
      unsigned word = hist[q&1][base+jj];
      unsigned cc = (q>>1) ? (word >> 16) : (word & 0xFFFFu);
      c16[jj] = cc; chunk += cc;
    }
    unsigned sc = chunk;
    #pragma unroll
    for (int off=1; off<64; off<<=1){
      unsigned o = __shfl_up(sc, (unsigned)off, 64);
      if (lane >= off) sc += o;
    }
    unsigned excl = sc - chunk;
    if (excl < KK && KK <= sc){
      unsigned acc = excl;
      #pragma unroll
      for (int jj=0;jj<16;jj++){
        if (acc + c16[jj] >= KK){ sB1[q] = (unsigned)(base+jj); sL1[q] = acc; break; }
        acc += c16[jj];
      }
    }
  }
  __syncthreads();
  unsigned B1r[4];
  #pragma unroll
  for (int q=0;q<4;q++) B1r[q] = sB1[q];
  unsigned* candk = &histf[0];           // hist dead; [q*CAP + slot]
  unsigned* candj = &histf[1024];

  // pass B: recompute keys; masks + candidate append (exact key in hand)
  unsigned lessm[4] = {0,0,0,0};
  unsigned cnt[4]   = {0,0,0,0};
  #pragma unroll 2
  for (int c=0;c<32;c++){
    int j = c*256 + t;
    float4 sj = sb[j];
    #pragma unroll
    for (int q=0;q<4;q++){
      unsigned k = r16_key(si[q], sj);
      if (j == iq[q]) k = 0x7F800000u;
      unsigned bin = k >> 21;
      if (bin < B1r[q]){ lessm[q] |= 1u<<c; cnt[q]++; }
      else if (bin == B1r[q]){
        unsigned slot = atomicAdd(&candCount[q], 1u);
        if (slot < CAP){ candk[q*CAP+slot] = k; candj[q*CAP+slot] = (unsigned)j; }
      }
    }
  }
  // per-query wave-scan compaction of strict-less
  unsigned vq[4];
  #pragma unroll
  for (int q=0;q<4;q++){
    unsigned v = cnt[q];
    #pragma unroll
    for (int off=1; off<64; off<<=1){
      unsigned o = __shfl_up(v, (unsigned)off, 64);
      if (lane >= off) v += o;
    }
    if (lane == 63) wtot[q][w] = v;
    vq[q] = v;
  }
  __syncthreads();
  #pragma unroll
  for (int q=0;q<4;q++){
    unsigned gbase = 0;
    for (int w2=0; w2<w; ++w2) gbase += wtot[q][w2];
    unsigned offs = gbase + vq[q] - cnt[q];
    unsigned m = lessm[q];
    while (m){
      int c = __builtin_ctz(m); m &= m-1u;
      sel[q][offs++] = c*256 + t;
    }
  }
  __syncthreads();

  // exact lex rank (key, j): 64 threads per query
  {
    int q = t >> 6;                     // = wave
    unsigned C1 = candCount[q]; if (C1 > CAP) C1 = CAP;
    unsigned L1 = sL1[q];
    for (unsigned idx = (unsigned)lane; idx < C1; idx += 64){
      unsigned k = candk[q*CAP+idx], j = candj[q*CAP+idx];
      unsigned rank = L1;
      for (unsigned u=0; u<C1; ++u){
        unsigned ku = candk[q*CAP+u], ju = candj[q*CAP+u];
        rank += (ku < k || (ku == k && ju < j)) ? 1u : 0u;
      }
      if (rank < KK){ sel[q][rank] = (int)j; selk[q][rank] = k; }
    }
  }
  __syncthreads();
  #pragma unroll
  for (int q=0;q<4;q++){
    if (t < (int)sL1[q]) selk[q][t] = r16_key(si[q], sb[sel[q][t]]);
  }
  __syncthreads();
  if (t < KK){
    #pragma unroll
    for (int q=0;q<4;q++) pots[q][t] = expf(-__uint_as_float(selk[q][t]));
  }
  __syncthreads();

  // aggregation: all queries' partials, 1 barrier, parallel finish
  float (*psum)[8][32] = (float(*)[8][32])&histf[0];     // 4*8*32 = 1024 f
  float (*pmax)[8][32] = (float(*)[8][32])&histf[1024];  // 1024 f
  int ch = t & 31, g = t >> 5;
  const float* hb2 = h + (size_t)b*NN*32;
  #pragma unroll
  for (int q=0;q<4;q++){
    float sum = 0.f, mx = -INFINITY;
    #pragma unroll
    for (int p=0;p<5;p++){
      int k2 = g*5 + p;
      float m = pots[q][k2] * hb2[(size_t)sel[q][k2]*32 + ch];
      sum += m; mx = fmaxf(mx, m);
    }
    psum[q][g][ch] = sum; pmax[q][g][ch] = mx;
  }
  __syncthreads();
  if (t < 128){
    int q = t >> 5, c2 = t & 31;
    float s = 0.f, m2 = -INFINITY;
    #pragma unroll
    for (int g2=0;g2<8;g2++){ s += psum[q][g2][c2]; m2 = fmaxf(m2, pmax[q][g2][c2]); }
    float* ab = agg + (size_t)(b*NN + i0 + q)*64;
    ab[c2]    = s / 40.0f;
    ab[32+c2] = m2;
  }
}

// ---------------- K4: lin + post-MLP + fused BN2 partials — UNCHANGED
__global__ __launch_bounds__(256) void r16_post(const float* __restrict__ agg,
    const float* __restrict__ x1, const float4* __restrict__ s4,
    const float* __restrict__ linW, const float* __restrict__ linb,
    const float* __restrict__ pW1, const float* __restrict__ pb1,
    const float* __restrict__ pW2, const float* __restrict__ pb2,
    float* __restrict__ outpre, float* __restrict__ part2)
{
  __shared__ float sLW[96*32], sPW1[67*32], sPW2[32*32];
  __shared__ float sLB[32], sPB1[32], sPB2[32];
  __shared__ float wls[4][32], wls2[4][32];
  int t = threadIdx.x;
  for (int i=t;i<96*32;i+=256) sLW[i]=linW[i];
  for (int i=t;i<67*32;i+=256) sPW1[i]=pW1[i];
  for (int i=t;i<32*32;i+=256) sPW2[i]=pW2[i];
  if (t<32){ sLB[t]=linb[t]; sPB1[t]=pb1[t]; sPB2[t]=pb2[t]; }
  __syncthreads();
  int node = blockIdx.x*256+t;
  float av[64], xv[32];
  #pragma unroll
  for (int i=0;i<64;i++) av[i]=agg[(size_t)node*64+i];
  #pragma unroll
  for (int i=0;i<32;i++) xv[i]=x1[(size_t)node*32+i];
  float4 sv = s4[node];
  float xgn[32];
  #pragma unroll
  for (int o=0;o<32;o++){
    float a = sLB[o];
    #pragma unroll
    for (int i=0;i<64;i++) a += av[i]*sLW[i*32+o];
    #pragma unroll
    for (int i=0;i<32;i++) a += xv[i]*sLW[(64+i)*32+o];
    xgn[o]=a;
  }
  float p1[32];
  #pragma unroll
  for (int o=0;o<32;o++){
    float a = sPB1[o];
    #pragma unroll
    for (int i=0;i<32;i++) a += xgn[i]*sPW1[i*32+o];
    a += sv.x*sPW1[32*32+o] + sv.y*sPW1[33*32+o] + sv.z*sPW1[34*32+o];
    #pragma unroll
    for (int i=0;i<32;i++) a += xv[i]*sPW1[(35+i)*32+o];
    p1[o]=r16_elu(a);
  }
  float p2[32];
  #pragma unroll
  for (int o=0;o<32;o++){
    float a = sPB2[o];
    #pragma unroll
    for (int i=0;i<32;i++) a += p1[i]*sPW2[i*32+o];
    p2[o] = r16_elu(a);
    outpre[(size_t)node*32+o] = p2[o];
  }
  int lane = t & 63, w = t >> 6;
  #pragma unroll
  for (int c=0;c<32;c++){
    float v = p2[c], v2 = p2[c]*p2[c];
    #pragma unroll
    for (int off=32; off; off>>=1){ v += __shfl_down(v,(unsigned)off,64); v2 += __shfl_down(v2,(unsigned)off,64); }
    if (lane==0){ wls[w][c]=v; wls2[w][c]=v2; }
  }
  __syncthreads();
  if (t < 32){
    part2[blockIdx.x*64 + t]      = wls[0][t]+wls[1][t]+wls[2][t]+wls[3][t];
    part2[blockIdx.x*64 + 32 + t] = wls2[0][t]+wls2[1][t]+wls2[2][t]+wls2[3][t];
  }
}

// ---------------- K5: fused sred2 + BN2 apply -> d_out — UNCHANGED
__global__ __launch_bounds__(256) void r16_bnout(const float* __restrict__ part2,
    const float* __restrict__ outpre,
    const float* __restrict__ g, const float* __restrict__ b,
    float* __restrict__ out)
{
  __shared__ float sstat[64];
  __shared__ float smu[32], sdev2[32], sg2[32], sb2[32];
  int t = threadIdx.x;
  if (t < 64){
    float s = 0.f;
    for (int b2=0;b2<64;b2++) s += part2[b2*64+t];
    sstat[t] = s;
  }
  __syncthreads();
  if (t < 32){
    float s = sstat[t], sq = sstat[32+t];
    float mu = s * (1.f/NODES);
    float var = sq*(1.f/NODES) - mu*mu;
    smu[t] = mu; sdev2[t] = sqrtf(var+1e-5f);
    sg2[t] = g[t]; sb2[t] = b[t];
  }
  __syncthreads();
  int idx = blockIdx.x*256 + t;
  int c = idx & 31;
  out[idx] = sg2[c]*(outpre[idx]-smu[c])/sdev2[c] + sb2[c];
}

extern "C" void kernel_launch(void* const* d_in, const int* in_sizes, int n_in,
                              void* d_out, int out_size, void* d_ws, size_t ws_size,
                              hipStream_t stream)
{
  (void)in_sizes; (void)n_in; (void)out_size; (void)ws_size;
  const float* x      = (const float*)d_in[0];
  const float* preW1  = (const float*)d_in[1];
  const float* preb1  = (const float*)d_in[2];
  const float* preW2  = (const float*)d_in[3];
  const float* preb2  = (const float*)d_in[4];
  const float* bn1g   = (const float*)d_in[5];
  const float* bn1b   = (const float*)d_in[6];
  const float* linsW  = (const float*)d_in[7];
  const float* linhW  = (const float*)d_in[8];
  const float* linhb  = (const float*)d_in[9];
  const float* linW   = (const float*)d_in[10];
  const float* linb   = (const float*)d_in[11];
  const float* postW1 = (const float*)d_in[12];
  const float* postb1 = (const float*)d_in[13];
  const float* postW2 = (const float*)d_in[14];
  const float* postb2 = (const float*)d_in[15];
  const float* bn2g   = (const float*)d_in[16];
  const float* bn2b   = (const float*)d_in[17];

  float* ws = (float*)d_ws;
  float* xpre   = ws;                          // NODES*32
  float* x1     = xpre   + (size_t)NODES*32;
  float* h      = x1     + (size_t)NODES*32;
  float* s4     = h      + (size_t)NODES*32;   // NODES*4 (16B-aligned offset)
  float* agg    = s4     + (size_t)NODES*4;    // NODES*64
  float* outpre = agg    + (size_t)NODES*64;   // NODES*32
  float* part1  = outpre + (size_t)NODES*32;   // 64*64
  float* part2  = part1  + 64*64;              // 64*64

  hipLaunchKernelGGL(r16_pre,    dim3(64),    dim3(256), 0, stream, x, preW1, preb1, preW2, preb2, xpre, part1);
  hipLaunchKernelGGL(r16_bnproj, dim3(64),    dim3(256), 0, stream, part1, xpre, bn1g, bn1b, linhW, linhb, linsW, x1, h, (float4*)s4);
  hipLaunchKernelGGL(r16_knn,    dim3(4096),  dim3(256), 0, stream, (const float4*)s4, h, agg);
  hipLaunchKernelGGL(r16_post,   dim3(64),    dim3(256), 0, stream, agg, x1, (const float4*)s4, linW, linb, postW1, postb1, postW2, postb2, outpre, part2);
  hipLaunchKernelGGL(r16_bnout,  dim3(2048),  dim3(256), 0, stream, part2, outpre, bn2g, bn2b, (float*)d_out);
}